// Round 1
// baseline (7245.511 us; speedup 1.0000x reference)
//
#include <hip/hip_runtime.h>

#define NNODES 50000
#define NEDGES 800000
#define NFEAT 512
#define NHID 64
#define NCLASSES 40
#define NLAYERS 10
#define ALPHA 0.8f

// h[n, j] = sum_k x[n,k] * W[k,j] + b[j]   (wave per node, lane per hid feature)
__global__ void linear_in_kernel(const float* __restrict__ x,
                                 const float* __restrict__ W,
                                 const float* __restrict__ b,
                                 float* __restrict__ h) {
    int gid = blockIdx.x * blockDim.x + threadIdx.x;
    int node = gid >> 6;   // 64 lanes (one wave) per node
    int j = gid & 63;
    if (node >= NNODES) return;
    const float* xr = x + (size_t)node * NFEAT;
    float acc = b[j];
#pragma unroll 8
    for (int k = 0; k < NFEAT; ++k) {
        acc = fmaf(xr[k], W[k * NHID + j], acc);
    }
    h[(size_t)node * NHID + j] = acc;
}

// h_next = (1-ALPHA) * h0   (float4 vectorized)
__global__ void init_next_kernel(const float* __restrict__ h0,
                                 float* __restrict__ h_next) {
    int gid = blockIdx.x * blockDim.x + threadIdx.x;
    int total4 = NNODES * NHID / 4;
    if (gid >= total4) return;
    float4 v = ((const float4*)h0)[gid];
    float s = 1.0f - ALPHA;
    float4 o;
    o.x = s * v.x; o.y = s * v.y; o.z = s * v.z; o.w = s * v.w;
    ((float4*)h_next)[gid] = o;
}

// For each edge e: h_next[dst] += ALPHA * w[e] * h_cur[src]
// 16 threads per edge, each owning one float4 (4 feats)
__global__ void spmm_scatter_kernel(const int* __restrict__ src,
                                    const int* __restrict__ dst,
                                    const float* __restrict__ ew,
                                    const float* __restrict__ h_cur,
                                    float* __restrict__ h_next) {
    long long gid = (long long)blockIdx.x * blockDim.x + threadIdx.x;
    int e = (int)(gid >> 4);
    int f = (int)(gid & 15) << 2;
    if (e >= NEDGES) return;
    int s = src[e];
    int d = dst[e];
    float ww = ALPHA * ew[e];
    float4 v = *(const float4*)(h_cur + (size_t)s * NHID + f);
    float* o = h_next + (size_t)d * NHID + f;
    atomicAdd(o + 0, ww * v.x);
    atomicAdd(o + 1, ww * v.y);
    atomicAdd(o + 2, ww * v.z);
    atomicAdd(o + 3, ww * v.w);
}

// out[n, c] = sum_k h[n,k] * W[k,c] + b[c]
__global__ void linear_out_kernel(const float* __restrict__ h,
                                  const float* __restrict__ W,
                                  const float* __restrict__ b,
                                  float* __restrict__ out) {
    int gid = blockIdx.x * blockDim.x + threadIdx.x;
    if (gid >= NNODES * NCLASSES) return;
    int node = gid / NCLASSES;
    int c = gid - node * NCLASSES;
    const float* hr = h + (size_t)node * NHID;
    float acc = b[c];
#pragma unroll
    for (int k = 0; k < NHID; ++k) {
        acc = fmaf(hr[k], W[k * NCLASSES + c], acc);
    }
    out[gid] = acc;
}

extern "C" void kernel_launch(void* const* d_in, const int* in_sizes, int n_in,
                              void* d_out, int out_size, void* d_ws, size_t ws_size,
                              hipStream_t stream) {
    const float* x     = (const float*)d_in[0];
    const int*   ei    = (const int*)d_in[1];   // [2, NEDGES]: row0=src, row1=dst
    const float* ew    = (const float*)d_in[2];
    const float* W_in  = (const float*)d_in[3];
    const float* b_in  = (const float*)d_in[4];
    const float* W_out = (const float*)d_in[5];
    const float* b_out = (const float*)d_in[6];
    float* out = (float*)d_out;

    const int HN = NNODES * NHID;  // 3.2M floats
    float* h0 = (float*)d_ws;
    float* ha = h0 + HN;
    float* hb = ha + HN;

    // h0 = x @ W_in + b_in
    {
        int threads = NNODES * 64;
        linear_in_kernel<<<(threads + 255) / 256, 256, 0, stream>>>(x, W_in, b_in, h0);
    }

    const int* src = ei;
    const int* dst = ei + NEDGES;

    float* cur = h0;
    float* nxt = ha;
    for (int l = 0; l < NLAYERS; ++l) {
        // nxt = 0.2 * h0
        init_next_kernel<<<(HN / 4 + 255) / 256, 256, 0, stream>>>(h0, nxt);
        // nxt += 0.8 * A @ cur
        long long threads = (long long)NEDGES * 16;
        spmm_scatter_kernel<<<(int)((threads + 255) / 256), 256, 0, stream>>>(
            src, dst, ew, cur, nxt);
        cur = nxt;
        nxt = (cur == ha) ? hb : ha;
    }

    // out = cur @ W_out + b_out
    {
        int threads = NNODES * NCLASSES;
        linear_out_kernel<<<(threads + 255) / 256, 256, 0, stream>>>(cur, W_out, b_out, out);
    }
}

// Round 2
// 1350.833 us; speedup vs baseline: 5.3637x; 5.3637x over previous
//
#include <hip/hip_runtime.h>

#define NNODES 50000
#define NEDGES 800000
#define NFEAT 512
#define NHID 64
#define NCLASSES 40
#define NLAYERS 10
#define ALPHA 0.8f

// ---------------- CSR build (once per call) ----------------

__global__ void zero_counts_kernel(int* __restrict__ counts) {
    int i = blockIdx.x * blockDim.x + threadIdx.x;
    if (i < NNODES) counts[i] = 0;
}

__global__ void hist_kernel(const int* __restrict__ dst, int* __restrict__ counts) {
    int e = blockIdx.x * blockDim.x + threadIdx.x;
    if (e >= NEDGES) return;
    atomicAdd(&counts[dst[e]], 1);
}

// single-block exclusive scan over NNODES counts -> row_ptr[NNODES+1], cursor copy
__global__ void scan_kernel(const int* __restrict__ counts,
                            int* __restrict__ row_ptr,
                            int* __restrict__ cursor) {
    __shared__ int sdata[1024];
    __shared__ int carry;
    int tid = threadIdx.x;
    if (tid == 0) carry = 0;
    __syncthreads();
    for (int base = 0; base < NNODES; base += 1024) {
        int i = base + tid;
        int v = (i < NNODES) ? counts[i] : 0;
        sdata[tid] = v;
        __syncthreads();
        for (int off = 1; off < 1024; off <<= 1) {
            int t = (tid >= off) ? sdata[tid - off] : 0;
            __syncthreads();
            sdata[tid] += t;
            __syncthreads();
        }
        int incl = sdata[tid];
        if (i < NNODES) {
            int excl = carry + incl - v;
            row_ptr[i] = excl;
            cursor[i] = excl;
        }
        __syncthreads();
        if (tid == 1023) carry += sdata[1023];
        __syncthreads();
    }
    if (tid == 0) row_ptr[NNODES] = carry;   // == NEDGES
}

// edata[pos] = (src, bitcast(ALPHA * w))  at pos = cursor[dst]++
__global__ void csr_scatter_kernel(const int* __restrict__ src,
                                   const int* __restrict__ dst,
                                   const float* __restrict__ ew,
                                   int* __restrict__ cursor,
                                   int2* __restrict__ edata) {
    int e = blockIdx.x * blockDim.x + threadIdx.x;
    if (e >= NEDGES) return;
    int d = dst[e];
    int pos = atomicAdd(&cursor[d], 1);
    int2 ed;
    ed.x = src[e];
    ed.y = __float_as_int(ALPHA * ew[e]);
    edata[pos] = ed;
}

// ---------------- dense kernels ----------------

// h[n, j] = sum_k x[n,k] * W[k,j] + b[j]   (wave per node, lane per hid feature)
__global__ void linear_in_kernel(const float* __restrict__ x,
                                 const float* __restrict__ W,
                                 const float* __restrict__ b,
                                 float* __restrict__ h) {
    int gid = blockIdx.x * blockDim.x + threadIdx.x;
    int node = gid >> 6;
    int j = gid & 63;
    if (node >= NNODES) return;
    const float* xr = x + (size_t)node * NFEAT;
    float acc = b[j];
#pragma unroll 8
    for (int k = 0; k < NFEAT; ++k) {
        acc = fmaf(xr[k], W[k * NHID + j], acc);
    }
    h[(size_t)node * NHID + j] = acc;
}

// pull SpMM: h_next[n,j] = 0.2*h0[n,j] + sum_{e in row n} w'_e * h_cur[src_e, j]
// (w' already includes ALPHA). One wave per node, lane j = feature.
__global__ void spmm_pull_kernel(const int2* __restrict__ edata,
                                 const int* __restrict__ row_ptr,
                                 const float* __restrict__ h_cur,
                                 const float* __restrict__ h0,
                                 float* __restrict__ h_next) {
    int gid = blockIdx.x * blockDim.x + threadIdx.x;
    int node = gid >> 6;
    int j = gid & 63;
    if (node >= NNODES) return;
    int beg = row_ptr[node];
    int end = row_ptr[node + 1];
    float acc = 0.0f;
    for (int p = beg; p < end; ++p) {
        int2 ed = edata[p];            // wave-uniform broadcast
        float w = __int_as_float(ed.y);
        acc = fmaf(w, h_cur[((size_t)ed.x << 6) + j], acc);
    }
    h_next[gid] = fmaf(1.0f - ALPHA, h0[gid], acc);
}

// out[n, c] = sum_k h[n,k] * W[k,c] + b[c]
__global__ void linear_out_kernel(const float* __restrict__ h,
                                  const float* __restrict__ W,
                                  const float* __restrict__ b,
                                  float* __restrict__ out) {
    int gid = blockIdx.x * blockDim.x + threadIdx.x;
    if (gid >= NNODES * NCLASSES) return;
    int node = gid / NCLASSES;
    int c = gid - node * NCLASSES;
    const float* hr = h + (size_t)node * NHID;
    float acc = b[c];
#pragma unroll
    for (int k = 0; k < NHID; ++k) {
        acc = fmaf(hr[k], W[k * NCLASSES + c], acc);
    }
    out[gid] = acc;
}

extern "C" void kernel_launch(void* const* d_in, const int* in_sizes, int n_in,
                              void* d_out, int out_size, void* d_ws, size_t ws_size,
                              hipStream_t stream) {
    const float* x     = (const float*)d_in[0];
    const int*   ei    = (const int*)d_in[1];   // [2, NEDGES]: row0=src, row1=dst
    const float* ew    = (const float*)d_in[2];
    const float* W_in  = (const float*)d_in[3];
    const float* b_in  = (const float*)d_in[4];
    const float* W_out = (const float*)d_in[5];
    const float* b_out = (const float*)d_in[6];
    float* out = (float*)d_out;

    const int HN = NNODES * NHID;        // 3.2M floats
    float* h0 = (float*)d_ws;            // 12.8 MB
    float* ha = h0 + HN;                 // 12.8 MB
    float* hb = ha + HN;                 // 12.8 MB
    int2*  edata   = (int2*)(hb + HN);   // 6.4 MB, 8B-aligned (38.4MB offset)
    int*   row_ptr = (int*)(edata + NEDGES);     // NNODES+1
    int*   cursor  = row_ptr + (NNODES + 1);
    int*   counts  = cursor + NNODES;

    const int* src = ei;
    const int* dst = ei + NEDGES;

    // ---- CSR build ----
    zero_counts_kernel<<<(NNODES + 255) / 256, 256, 0, stream>>>(counts);
    hist_kernel<<<(NEDGES + 255) / 256, 256, 0, stream>>>(dst, counts);
    scan_kernel<<<1, 1024, 0, stream>>>(counts, row_ptr, cursor);
    csr_scatter_kernel<<<(NEDGES + 255) / 256, 256, 0, stream>>>(src, dst, ew, cursor, edata);

    // ---- h0 = x @ W_in + b_in ----
    linear_in_kernel<<<(NNODES * 64 + 255) / 256, 256, 0, stream>>>(x, W_in, b_in, h0);

    // ---- 10 APPNP layers (pull, atomic-free) ----
    float* cur = h0;
    float* nxt = ha;
    for (int l = 0; l < NLAYERS; ++l) {
        spmm_pull_kernel<<<(NNODES * 64 + 255) / 256, 256, 0, stream>>>(
            edata, row_ptr, cur, h0, nxt);
        cur = nxt;
        nxt = (cur == ha) ? hb : ha;
    }

    // ---- out = cur @ W_out + b_out ----
    linear_out_kernel<<<(NNODES * NCLASSES + 255) / 256, 256, 0, stream>>>(
        cur, W_out, b_out, out);
}

// Round 3
// 500.798 us; speedup vs baseline: 14.4679x; 2.6974x over previous
//
#include <hip/hip_runtime.h>

#define NNODES 50000
#define NEDGES 800000
#define NFEAT 512
#define NHID 64
#define NCLASSES 40
#define NLAYERS 10
#define ALPHA 0.8f

// ---------------- CSR build (once per call) ----------------

__global__ void zero_counts_kernel(int* __restrict__ counts) {
    int i = blockIdx.x * blockDim.x + threadIdx.x;
    if (i < NNODES) counts[i] = 0;
}

__global__ void hist_kernel(const int* __restrict__ dst, int* __restrict__ counts) {
    int e = blockIdx.x * blockDim.x + threadIdx.x;
    if (e >= NEDGES) return;
    atomicAdd(&counts[dst[e]], 1);
}

// two-level scan: (1) per-block scan + block sums
__global__ void scan1_kernel(const int* __restrict__ counts,
                             int* __restrict__ row_ptr,
                             int* __restrict__ bsum) {
    __shared__ int sd[1024];
    int tid = threadIdx.x;
    int i = blockIdx.x * 1024 + tid;
    int v = (i < NNODES) ? counts[i] : 0;
    sd[tid] = v;
    __syncthreads();
    for (int off = 1; off < 1024; off <<= 1) {
        int t = (tid >= off) ? sd[tid - off] : 0;
        __syncthreads();
        sd[tid] += t;
        __syncthreads();
    }
    if (i < NNODES) row_ptr[i] = sd[tid] - v;   // block-local exclusive
    if (tid == 1023) bsum[blockIdx.x] = sd[1023];
}

// (2) 1-wave scan of 49 block sums
__global__ void scan2_kernel(const int* __restrict__ bsum, int* __restrict__ boff) {
    int tid = threadIdx.x;
    const int NB = (NNODES + 1023) / 1024;   // 49
    int v0 = (tid < NB) ? bsum[tid] : 0;
    int v = v0;
#pragma unroll
    for (int off = 1; off < 64; off <<= 1) {
        int t = __shfl_up(v, off);
        if (tid >= off) v += t;
    }
    if (tid < NB) boff[tid] = v - v0;        // exclusive
    if (tid == NB - 1) boff[NB] = v;         // total == NEDGES
}

// (3) add block offsets, fill cursor, write row_ptr[NNODES]
__global__ void scan3_kernel(const int* __restrict__ boff,
                             int* __restrict__ row_ptr,
                             int* __restrict__ cursor) {
    int i = blockIdx.x * blockDim.x + threadIdx.x;
    if (i < NNODES) {
        int rp = row_ptr[i] + boff[i >> 10];
        row_ptr[i] = rp;
        cursor[i] = rp;
    } else if (i == NNODES) {
        row_ptr[NNODES] = boff[(NNODES + 1023) / 1024];
    }
}

// edata[pos] = (src, bitcast(ALPHA * w)) at pos = cursor[dst]++
__global__ void csr_scatter_kernel(const int* __restrict__ src,
                                   const int* __restrict__ dst,
                                   const float* __restrict__ ew,
                                   int* __restrict__ cursor,
                                   int2* __restrict__ edata) {
    int e = blockIdx.x * blockDim.x + threadIdx.x;
    if (e >= NEDGES) return;
    int d = dst[e];
    int pos = atomicAdd(&cursor[d], 1);
    int2 ed;
    ed.x = src[e];
    ed.y = __float_as_int(ALPHA * ew[e]);
    edata[pos] = ed;
}

// ---------------- dense kernels ----------------

// h = x @ W_in + b_in. Block: 64 nodes x 64 cols, 256 threads.
// Thread: 8 nodes x 2 cols register tile; x staged in LDS transposed.
#define LIN_KC 32
__global__ __launch_bounds__(256) void linear_in_kernel(
        const float* __restrict__ x, const float* __restrict__ W,
        const float* __restrict__ b, float* __restrict__ h) {
    __shared__ float xs[LIN_KC][68];   // [k][node], pad 64->68 (16B-aligned rows)
    int tid = threadIdx.x;
    int nb = blockIdx.x * 64;          // node base
    int jp = (tid & 31) * 2;           // col pair
    int ng = tid >> 5;                 // node subgroup 0..7
    float acc[8][2];
#pragma unroll
    for (int i = 0; i < 8; ++i) { acc[i][0] = 0.f; acc[i][1] = 0.f; }

    for (int kc = 0; kc < NFEAT; kc += LIN_KC) {
        // stage x[nb..nb+63][kc..kc+31] transposed: 512 float4, 2 per thread
#pragma unroll
        for (int q = 0; q < 2; ++q) {
            int li = tid + q * 256;
            int r = li >> 3;           // node 0..63
            int f4 = li & 7;           // k quad 0..7
            int row = nb + r;
            float4 v = make_float4(0.f, 0.f, 0.f, 0.f);
            if (row < NNODES)
                v = *(const float4*)(x + (size_t)row * NFEAT + kc + f4 * 4);
            xs[f4 * 4 + 0][r] = v.x;
            xs[f4 * 4 + 1][r] = v.y;
            xs[f4 * 4 + 2][r] = v.z;
            xs[f4 * 4 + 3][r] = v.w;
        }
        __syncthreads();
#pragma unroll
        for (int k = 0; k < LIN_KC; ++k) {
            float2 w = *(const float2*)(W + (size_t)(kc + k) * NHID + jp);
            const float* xr = &xs[k][ng * 8];
            float a[8];
            *(float4*)(a)     = *(const float4*)(xr);
            *(float4*)(a + 4) = *(const float4*)(xr + 4);
#pragma unroll
            for (int i = 0; i < 8; ++i) {
                acc[i][0] = fmaf(a[i], w.x, acc[i][0]);
                acc[i][1] = fmaf(a[i], w.y, acc[i][1]);
            }
        }
        __syncthreads();
    }
    float2 bb = *(const float2*)(b + jp);
#pragma unroll
    for (int i = 0; i < 8; ++i) {
        int n = nb + ng * 8 + i;
        if (n < NNODES) {
            float2 o;
            o.x = acc[i][0] + bb.x;
            o.y = acc[i][1] + bb.y;
            *(float2*)(h + (size_t)n * NHID + jp) = o;
        }
    }
}

// pull SpMM: 4 nodes per wave, 16 lanes x float4 per node, 2 edges in flight.
__global__ __launch_bounds__(256) void spmm_pull_kernel(
        const int2* __restrict__ edata, const int* __restrict__ row_ptr,
        const float* __restrict__ h_cur, const float* __restrict__ h0,
        float* __restrict__ h_next) {
    int gid = blockIdx.x * blockDim.x + threadIdx.x;
    int wave = gid >> 6;
    int lane = threadIdx.x & 63;
    int grp = lane >> 4;               // 0..3
    int fl = (lane & 15) << 2;         // feature base
    int node = wave * 4 + grp;         // NNODES % 4 == 0, no guard needed
    int beg = row_ptr[node];
    int deg = row_ptr[node + 1] - beg;
    int steps = deg;
    steps = max(steps, __shfl_xor(steps, 16));
    steps = max(steps, __shfl_xor(steps, 32));

    float4 acc = make_float4(0.f, 0.f, 0.f, 0.f);
    int t = 0;
    for (; t + 1 < steps; t += 2) {
        bool v0 = (t < deg), v1 = (t + 1 < deg);
        int2 e0 = edata[v0 ? (beg + t) : 0];
        int2 e1 = edata[v1 ? (beg + t + 1) : 0];
        float w0 = v0 ? __int_as_float(e0.y) : 0.f;
        float w1 = v1 ? __int_as_float(e1.y) : 0.f;
        float4 g0 = *(const float4*)(h_cur + ((size_t)e0.x << 6) + fl);
        float4 g1 = *(const float4*)(h_cur + ((size_t)e1.x << 6) + fl);
        acc.x = fmaf(w0, g0.x, acc.x); acc.y = fmaf(w0, g0.y, acc.y);
        acc.z = fmaf(w0, g0.z, acc.z); acc.w = fmaf(w0, g0.w, acc.w);
        acc.x = fmaf(w1, g1.x, acc.x); acc.y = fmaf(w1, g1.y, acc.y);
        acc.z = fmaf(w1, g1.z, acc.z); acc.w = fmaf(w1, g1.w, acc.w);
    }
    if (t < steps) {
        bool v0 = (t < deg);
        int2 e0 = edata[v0 ? (beg + t) : 0];
        float w0 = v0 ? __int_as_float(e0.y) : 0.f;
        float4 g0 = *(const float4*)(h_cur + ((size_t)e0.x << 6) + fl);
        acc.x = fmaf(w0, g0.x, acc.x); acc.y = fmaf(w0, g0.y, acc.y);
        acc.z = fmaf(w0, g0.z, acc.z); acc.w = fmaf(w0, g0.w, acc.w);
    }
    size_t o = ((size_t)node << 6) + fl;
    float4 hv = *(const float4*)(h0 + o);
    float4 r;
    const float s = 1.0f - ALPHA;
    r.x = fmaf(s, hv.x, acc.x); r.y = fmaf(s, hv.y, acc.y);
    r.z = fmaf(s, hv.z, acc.z); r.w = fmaf(s, hv.w, acc.w);
    *(float4*)(h_next + o) = r;
}

// out = h @ W_out + b_out. Thread per node; W_out (10 KB) in LDS.
__global__ __launch_bounds__(256) void linear_out_kernel(
        const float* __restrict__ h, const float* __restrict__ W,
        const float* __restrict__ b, float* __restrict__ out) {
    __shared__ float ws[NHID * NCLASSES];
    __shared__ float bs[NCLASSES];
    int tid = threadIdx.x;
    for (int i = tid; i < NHID * NCLASSES; i += 256) ws[i] = W[i];
    if (tid < NCLASSES) bs[tid] = b[tid];
    __syncthreads();
    int node = blockIdx.x * 256 + tid;
    if (node >= NNODES) return;
    float acc[NCLASSES];
#pragma unroll
    for (int c = 0; c < NCLASSES; ++c) acc[c] = bs[c];
    const float* hr = h + (size_t)node * NHID;
#pragma unroll
    for (int kq = 0; kq < NHID; kq += 16) {
        float hv[16];
        *(float4*)(hv)      = *(const float4*)(hr + kq);
        *(float4*)(hv + 4)  = *(const float4*)(hr + kq + 4);
        *(float4*)(hv + 8)  = *(const float4*)(hr + kq + 8);
        *(float4*)(hv + 12) = *(const float4*)(hr + kq + 12);
#pragma unroll
        for (int kk = 0; kk < 16; ++kk) {
#pragma unroll
            for (int c = 0; c < NCLASSES; ++c)
                acc[c] = fmaf(hv[kk], ws[(kq + kk) * NCLASSES + c], acc[c]);
        }
    }
#pragma unroll
    for (int c = 0; c < NCLASSES; ++c)
        out[(size_t)node * NCLASSES + c] = acc[c];
}

extern "C" void kernel_launch(void* const* d_in, const int* in_sizes, int n_in,
                              void* d_out, int out_size, void* d_ws, size_t ws_size,
                              hipStream_t stream) {
    const float* x     = (const float*)d_in[0];
    const int*   ei    = (const int*)d_in[1];
    const float* ew    = (const float*)d_in[2];
    const float* W_in  = (const float*)d_in[3];
    const float* b_in  = (const float*)d_in[4];
    const float* W_out = (const float*)d_in[5];
    const float* b_out = (const float*)d_in[6];
    float* out = (float*)d_out;

    const int HN = NNODES * NHID;
    float* h0 = (float*)d_ws;
    float* ha = h0 + HN;
    float* hb = ha + HN;
    int2*  edata   = (int2*)(hb + HN);
    int*   row_ptr = (int*)(edata + NEDGES);
    int*   cursor  = row_ptr + (NNODES + 1);
    int*   counts  = cursor + NNODES;
    int*   bsum    = counts + NNODES;
    int*   boff    = bsum + 64;

    const int* src = ei;
    const int* dst = ei + NEDGES;

    // ---- CSR build ----
    zero_counts_kernel<<<(NNODES + 255) / 256, 256, 0, stream>>>(counts);
    hist_kernel<<<(NEDGES + 255) / 256, 256, 0, stream>>>(dst, counts);
    const int NB = (NNODES + 1023) / 1024;
    scan1_kernel<<<NB, 1024, 0, stream>>>(counts, row_ptr, bsum);
    scan2_kernel<<<1, 64, 0, stream>>>(bsum, boff);
    scan3_kernel<<<(NNODES + 256) / 256, 256, 0, stream>>>(boff, row_ptr, cursor);
    csr_scatter_kernel<<<(NEDGES + 255) / 256, 256, 0, stream>>>(src, dst, ew, cursor, edata);

    // ---- h0 = x @ W_in + b_in ----
    linear_in_kernel<<<(NNODES + 63) / 64, 256, 0, stream>>>(x, W_in, b_in, h0);

    // ---- 10 APPNP layers ----
    float* cur = h0;
    float* nxt = ha;
    for (int l = 0; l < NLAYERS; ++l) {
        spmm_pull_kernel<<<(NNODES / 4 * 64) / 256, 256, 0, stream>>>(
            edata, row_ptr, cur, h0, nxt);
        cur = nxt;
        nxt = (cur == ha) ? hb : ha;
    }

    // ---- out = cur @ W_out + b_out ----
    linear_out_kernel<<<(NNODES + 255) / 256, 256, 0, stream>>>(cur, W_out, b_out, out);
}